// Round 1
// baseline (2675.429 us; speedup 1.0000x reference)
//
#include <hip/hip_runtime.h>

// APPNP: h0 = relu(x@W1+b1)@W2+b2 ; 10x h = 0.99*SpMM(h) + 0.01*h
// Plan: bf16 MFMA for the two GEMMs, on-device CSR build, wave-per-row
// gather SpMM with bf16 h storage (fp32 accumulate), final step writes fp32.
// Workspace use: ~104 MB.

#define N_NODES 100000
#define N_EDGES 3200000
#define IN_F    512
#define HID_F   256
#define OUT_F   64

typedef short bf16x8 __attribute__((ext_vector_type(8)));
typedef float f32x4  __attribute__((ext_vector_type(4)));

__device__ __forceinline__ unsigned short f2bf(float f) {
    unsigned int u = __float_as_uint(f);
    unsigned int r = (u + 0x7FFFu + ((u >> 16) & 1u)) >> 16;  // RNE
    return (unsigned short)r;
}
__device__ __forceinline__ float bf2f(unsigned short h) {
    return __uint_as_float(((unsigned int)h) << 16);
}

// ---------------- weight cast+transpose ----------------
__global__ void cast_transpose_w1(const float* __restrict__ w, unsigned short* __restrict__ wt) {
    int idx = blockIdx.x * blockDim.x + threadIdx.x;   // over 512*256
    if (idx >= IN_F * HID_F) return;
    int k = idx / HID_F, n = idx % HID_F;
    wt[(size_t)n * IN_F + k] = f2bf(w[idx]);           // W1T [HID_F][IN_F]
}
__global__ void cast_transpose_w2(const float* __restrict__ w, unsigned short* __restrict__ wt) {
    int idx = blockIdx.x * blockDim.x + threadIdx.x;   // over 256*64
    if (idx >= HID_F * OUT_F) return;
    int k = idx / OUT_F, n = idx % OUT_F;
    wt[(size_t)n * HID_F + k] = f2bf(w[idx]);          // W2T [OUT_F][HID_F]
}

// ---------------- GEMM1: h1 = relu(x @ W1 + b1), bf16 out ----------------
// block = 512 threads = 8 waves; tile BM=64 x BN=256 (full N); wave: 32x64.
__global__ __launch_bounds__(512) void gemm1(const float* __restrict__ x,
                                             const unsigned short* __restrict__ w1t,
                                             const float* __restrict__ b1,
                                             unsigned short* __restrict__ h1) {
    int tid  = threadIdx.x;
    int lane = tid & 63;
    int w    = tid >> 6;     // 0..7
    int wm   = w >> 2;       // 0..1
    int wn   = w & 3;        // 0..3
    int quad = lane >> 4;    // 0..3
    int lm   = lane & 15;
    int m0 = blockIdx.x * 64 + wm * 32;
    int n0 = wn * 64;

    f32x4 acc[2][4];
    for (int i = 0; i < 2; ++i)
        for (int j = 0; j < 4; ++j)
            acc[i][j] = (f32x4){0.f, 0.f, 0.f, 0.f};

    for (int kk = 0; kk < IN_F; kk += 32) {
        bf16x8 a[2], b[4];
        for (int i = 0; i < 2; ++i) {
            int m = m0 + i * 16 + lm;
            if (m > N_NODES - 1) m = N_NODES - 1;            // clamp loads, mask stores
            const float* ap = x + (size_t)m * IN_F + kk + quad * 8;
            float4 f0 = *(const float4*)ap;
            float4 f1 = *(const float4*)(ap + 4);
            union { bf16x8 v; unsigned short u[8]; } t;
            t.u[0] = f2bf(f0.x); t.u[1] = f2bf(f0.y); t.u[2] = f2bf(f0.z); t.u[3] = f2bf(f0.w);
            t.u[4] = f2bf(f1.x); t.u[5] = f2bf(f1.y); t.u[6] = f2bf(f1.z); t.u[7] = f2bf(f1.w);
            a[i] = t.v;
        }
        for (int j = 0; j < 4; ++j) {
            int n = n0 + j * 16 + lm;
            b[j] = *(const bf16x8*)(w1t + (size_t)n * IN_F + kk + quad * 8);
        }
        for (int i = 0; i < 2; ++i)
            for (int j = 0; j < 4; ++j)
                acc[i][j] = __builtin_amdgcn_mfma_f32_16x16x32_bf16(a[i], b[j], acc[i][j], 0, 0, 0);
    }

    for (int i = 0; i < 2; ++i)
        for (int j = 0; j < 4; ++j) {
            int n = n0 + j * 16 + lm;
            float bias = b1[n];
            for (int r = 0; r < 4; ++r) {
                int m = m0 + i * 16 + quad * 4 + r;   // C/D: row=(lane>>4)*4+reg, col=lane&15
                if (m < N_NODES) {
                    float v = acc[i][j][r] + bias;
                    v = v > 0.f ? v : 0.f;
                    h1[(size_t)m * HID_F + n] = f2bf(v);
                }
            }
        }
}

// ---------------- GEMM2: h0 = h1 @ W2 + b2, bf16 out ----------------
// block = 256 threads = 4 waves; tile BM=64 x BN=64; wave: 32x32.
__global__ __launch_bounds__(256) void gemm2(const unsigned short* __restrict__ h1,
                                             const unsigned short* __restrict__ w2t,
                                             const float* __restrict__ b2,
                                             unsigned short* __restrict__ h0) {
    int tid  = threadIdx.x;
    int lane = tid & 63;
    int w    = tid >> 6;     // 0..3
    int wm   = w >> 1;       // 0..1
    int wn   = w & 1;        // 0..1
    int quad = lane >> 4;
    int lm   = lane & 15;
    int m0 = blockIdx.x * 64 + wm * 32;
    int n0 = wn * 32;

    f32x4 acc[2][2];
    for (int i = 0; i < 2; ++i)
        for (int j = 0; j < 2; ++j)
            acc[i][j] = (f32x4){0.f, 0.f, 0.f, 0.f};

    for (int kk = 0; kk < HID_F; kk += 32) {
        bf16x8 a[2], b[2];
        for (int i = 0; i < 2; ++i) {
            int m = m0 + i * 16 + lm;
            if (m > N_NODES - 1) m = N_NODES - 1;
            a[i] = *(const bf16x8*)(h1 + (size_t)m * HID_F + kk + quad * 8);
        }
        for (int j = 0; j < 2; ++j) {
            int n = n0 + j * 16 + lm;
            b[j] = *(const bf16x8*)(w2t + (size_t)n * HID_F + kk + quad * 8);
        }
        for (int i = 0; i < 2; ++i)
            for (int j = 0; j < 2; ++j)
                acc[i][j] = __builtin_amdgcn_mfma_f32_16x16x32_bf16(a[i], b[j], acc[i][j], 0, 0, 0);
    }

    for (int i = 0; i < 2; ++i)
        for (int j = 0; j < 2; ++j) {
            int n = n0 + j * 16 + lm;
            float bias = b2[n];
            for (int r = 0; r < 4; ++r) {
                int m = m0 + i * 16 + quad * 4 + r;
                if (m < N_NODES) {
                    float v = acc[i][j][r] + bias;
                    h0[(size_t)m * OUT_F + n] = f2bf(v);
                }
            }
        }
}

// ---------------- CSR build ----------------
__global__ void count_edges(const int* __restrict__ row, int* __restrict__ cnt) {
    int e = blockIdx.x * blockDim.x + threadIdx.x;
    if (e < N_EDGES) atomicAdd(&cnt[row[e]], 1);
}

// single-block scan: rowptr[0]=0, rowptr[i+1] = prefix-inclusive(cnt[0..i])
__global__ __launch_bounds__(1024) void scan_kernel(const int* __restrict__ cnt,
                                                    int* __restrict__ rowptr, int n) {
    __shared__ int warpsum[16];
    __shared__ int sbase;
    int tid = threadIdx.x;
    if (tid == 0) { sbase = 0; rowptr[0] = 0; }
    __syncthreads();
    for (int i0 = 0; i0 < n; i0 += 1024) {
        int i = i0 + tid;
        int v = (i < n) ? cnt[i] : 0;
        int incl = v;
        for (int d = 1; d < 64; d <<= 1) {
            int t = __shfl_up(incl, d);
            if ((tid & 63) >= d) incl += t;
        }
        int wid = tid >> 6;
        if ((tid & 63) == 63) warpsum[wid] = incl;
        __syncthreads();
        if (wid == 0) {
            int wv = (tid < 16) ? warpsum[tid] : 0;
            for (int d = 1; d < 16; d <<= 1) {
                int t = __shfl_up(wv, d);
                if ((tid & 63) >= d) wv += t;
            }
            if (tid < 16) warpsum[tid] = wv;
        }
        __syncthreads();
        int waveoff = (wid > 0) ? warpsum[wid - 1] : 0;
        int total   = warpsum[15];
        int base    = sbase;
        if (i < n) rowptr[i + 1] = base + waveoff + incl;
        __syncthreads();
        if (tid == 0) sbase = base + total;
        __syncthreads();
    }
}

__global__ void cursor_init(const int* __restrict__ rowptr, int* __restrict__ cur) {
    int i = blockIdx.x * blockDim.x + threadIdx.x;
    if (i < N_NODES) cur[i] = rowptr[i];
}

__global__ void scatter_edges(const int* __restrict__ row, const int* __restrict__ col,
                              const float* __restrict__ ew, int* __restrict__ cur,
                              int2* __restrict__ colw) {
    int e = blockIdx.x * blockDim.x + threadIdx.x;
    if (e < N_EDGES) {
        int p = atomicAdd(&cur[row[e]], 1);
        colw[p] = make_int2(col[e], __float_as_int(ew[e]));
    }
}

// ---------------- propagation: one wave per row, lane = feature ----------------
__global__ __launch_bounds__(256) void prop(const unsigned short* __restrict__ hin,
                                            const int* __restrict__ rowptr,
                                            const int2* __restrict__ colw,
                                            unsigned short* __restrict__ hout,
                                            float* __restrict__ fout, int is_final) {
    int lane = threadIdx.x & 63;
    int r = blockIdx.x * 4 + (threadIdx.x >> 6);
    int ru = __builtin_amdgcn_readfirstlane(r);       // force wave-uniform (scalar loads)
    int s = rowptr[ru];
    int e = rowptr[ru + 1];
    float acc = 0.f;
    for (int i = s; i < e; ++i) {
        int2 cw = colw[i];                            // wave-uniform -> broadcast
        acc += __int_as_float(cw.y) * bf2f(hin[(size_t)cw.x * OUT_F + lane]);
    }
    float res = 0.99f * acc + 0.01f * bf2f(hin[(size_t)ru * OUT_F + lane]);
    size_t o = (size_t)ru * OUT_F + lane;
    if (is_final) fout[o] = res;
    else          hout[o] = f2bf(res);
}

extern "C" void kernel_launch(void* const* d_in, const int* in_sizes, int n_in,
                              void* d_out, int out_size, void* d_ws, size_t ws_size,
                              hipStream_t stream) {
    (void)in_sizes; (void)n_in; (void)out_size; (void)ws_size;
    const float* x  = (const float*)d_in[0];
    const float* W1 = (const float*)d_in[1];
    const float* b1 = (const float*)d_in[2];
    const float* W2 = (const float*)d_in[3];
    const float* b2 = (const float*)d_in[4];
    const float* ew = (const float*)d_in[5];
    const int*  row = (const int*)d_in[6];
    const int*  col = (const int*)d_in[7];
    float* out = (float*)d_out;

    char* ws = (char*)d_ws;
    size_t off = 0;
    auto alloc = [&](size_t b) { char* p = ws + off; off += (b + 255) & ~(size_t)255; return p; };
    unsigned short* w1t = (unsigned short*)alloc((size_t)IN_F * HID_F * 2);
    unsigned short* w2t = (unsigned short*)alloc((size_t)HID_F * OUT_F * 2);
    unsigned short* h1  = (unsigned short*)alloc((size_t)N_NODES * HID_F * 2);
    unsigned short* hb0 = (unsigned short*)alloc((size_t)N_NODES * OUT_F * 2);
    unsigned short* hb1 = (unsigned short*)alloc((size_t)N_NODES * OUT_F * 2);
    int*  rowptr = (int*)alloc((size_t)(N_NODES + 1) * 4);
    int*  cnt    = (int*)alloc((size_t)N_NODES * 4);
    int2* colw   = (int2*)alloc((size_t)N_EDGES * 8);

    cast_transpose_w1<<<(IN_F * HID_F + 255) / 256, 256, 0, stream>>>(W1, w1t);
    cast_transpose_w2<<<(HID_F * OUT_F + 255) / 256, 256, 0, stream>>>(W2, w2t);
    gemm1<<<(N_NODES + 63) / 64, 512, 0, stream>>>(x, w1t, b1, h1);
    gemm2<<<(N_NODES + 63) / 64, 256, 0, stream>>>(h1, w2t, b2, hb0);

    hipMemsetAsync(cnt, 0, (size_t)N_NODES * 4, stream);
    count_edges<<<(N_EDGES + 255) / 256, 256, 0, stream>>>(row, cnt);
    scan_kernel<<<1, 1024, 0, stream>>>(cnt, rowptr, N_NODES);
    cursor_init<<<(N_NODES + 255) / 256, 256, 0, stream>>>(rowptr, cnt);
    scatter_edges<<<(N_EDGES + 255) / 256, 256, 0, stream>>>(row, col, ew, cnt, colw);

    const unsigned short* pin = hb0;
    for (int s = 0; s < 10; ++s) {
        int last = (s == 9);
        unsigned short* pout = (s & 1) ? hb0 : hb1;
        prop<<<N_NODES / 4, 256, 0, stream>>>(pin, rowptr, colw, pout, out, last);
        pin = pout;
    }
}

// Round 2
// 1680.477 us; speedup vs baseline: 1.5921x; 1.5921x over previous
//
#include <hip/hip_runtime.h>

// APPNP: h0 = relu(x@W1+b1)@W2+b2 ; 10x h = 0.99*SpMM(h) + 0.01*h
// bf16 MFMA GEMMs, on-device CSR build, gather SpMM with bf16 h storage.
// R2: prop reworked — 4 edges per wave-iteration (16 lanes/edge, ushort4
// feature-quad per lane), guard-free main loop + tail, shfl_xor combine.

#define N_NODES 100000
#define N_EDGES 3200000
#define IN_F    512
#define HID_F   256
#define OUT_F   64

typedef short bf16x8 __attribute__((ext_vector_type(8)));
typedef float f32x4  __attribute__((ext_vector_type(4)));

__device__ __forceinline__ unsigned short f2bf(float f) {
    unsigned int u = __float_as_uint(f);
    unsigned int r = (u + 0x7FFFu + ((u >> 16) & 1u)) >> 16;  // RNE
    return (unsigned short)r;
}
__device__ __forceinline__ float bf2f(unsigned short h) {
    return __uint_as_float(((unsigned int)h) << 16);
}

// ---------------- weight cast+transpose ----------------
__global__ void cast_transpose_w1(const float* __restrict__ w, unsigned short* __restrict__ wt) {
    int idx = blockIdx.x * blockDim.x + threadIdx.x;   // over 512*256
    if (idx >= IN_F * HID_F) return;
    int k = idx / HID_F, n = idx % HID_F;
    wt[(size_t)n * IN_F + k] = f2bf(w[idx]);           // W1T [HID_F][IN_F]
}
__global__ void cast_transpose_w2(const float* __restrict__ w, unsigned short* __restrict__ wt) {
    int idx = blockIdx.x * blockDim.x + threadIdx.x;   // over 256*64
    if (idx >= HID_F * OUT_F) return;
    int k = idx / OUT_F, n = idx % OUT_F;
    wt[(size_t)n * HID_F + k] = f2bf(w[idx]);          // W2T [OUT_F][HID_F]
}

// ---------------- GEMM1: h1 = relu(x @ W1 + b1), bf16 out ----------------
__global__ __launch_bounds__(512) void gemm1(const float* __restrict__ x,
                                             const unsigned short* __restrict__ w1t,
                                             const float* __restrict__ b1,
                                             unsigned short* __restrict__ h1) {
    int tid  = threadIdx.x;
    int lane = tid & 63;
    int w    = tid >> 6;     // 0..7
    int wm   = w >> 2;       // 0..1
    int wn   = w & 3;        // 0..3
    int quad = lane >> 4;    // 0..3
    int lm   = lane & 15;
    int m0 = blockIdx.x * 64 + wm * 32;
    int n0 = wn * 64;

    f32x4 acc[2][4];
    for (int i = 0; i < 2; ++i)
        for (int j = 0; j < 4; ++j)
            acc[i][j] = (f32x4){0.f, 0.f, 0.f, 0.f};

    for (int kk = 0; kk < IN_F; kk += 32) {
        bf16x8 a[2], b[4];
        for (int i = 0; i < 2; ++i) {
            int m = m0 + i * 16 + lm;
            if (m > N_NODES - 1) m = N_NODES - 1;            // clamp loads, mask stores
            const float* ap = x + (size_t)m * IN_F + kk + quad * 8;
            float4 f0 = *(const float4*)ap;
            float4 f1 = *(const float4*)(ap + 4);
            union { bf16x8 v; unsigned short u[8]; } t;
            t.u[0] = f2bf(f0.x); t.u[1] = f2bf(f0.y); t.u[2] = f2bf(f0.z); t.u[3] = f2bf(f0.w);
            t.u[4] = f2bf(f1.x); t.u[5] = f2bf(f1.y); t.u[6] = f2bf(f1.z); t.u[7] = f2bf(f1.w);
            a[i] = t.v;
        }
        for (int j = 0; j < 4; ++j) {
            int n = n0 + j * 16 + lm;
            b[j] = *(const bf16x8*)(w1t + (size_t)n * IN_F + kk + quad * 8);
        }
        for (int i = 0; i < 2; ++i)
            for (int j = 0; j < 4; ++j)
                acc[i][j] = __builtin_amdgcn_mfma_f32_16x16x32_bf16(a[i], b[j], acc[i][j], 0, 0, 0);
    }

    for (int i = 0; i < 2; ++i)
        for (int j = 0; j < 4; ++j) {
            int n = n0 + j * 16 + lm;
            float bias = b1[n];
            for (int r = 0; r < 4; ++r) {
                int m = m0 + i * 16 + quad * 4 + r;   // C/D: row=(lane>>4)*4+reg, col=lane&15
                if (m < N_NODES) {
                    float v = acc[i][j][r] + bias;
                    v = v > 0.f ? v : 0.f;
                    h1[(size_t)m * HID_F + n] = f2bf(v);
                }
            }
        }
}

// ---------------- GEMM2: h0 = h1 @ W2 + b2, bf16 out ----------------
__global__ __launch_bounds__(256) void gemm2(const unsigned short* __restrict__ h1,
                                             const unsigned short* __restrict__ w2t,
                                             const float* __restrict__ b2,
                                             unsigned short* __restrict__ h0) {
    int tid  = threadIdx.x;
    int lane = tid & 63;
    int w    = tid >> 6;     // 0..3
    int wm   = w >> 1;       // 0..1
    int wn   = w & 1;        // 0..1
    int quad = lane >> 4;
    int lm   = lane & 15;
    int m0 = blockIdx.x * 64 + wm * 32;
    int n0 = wn * 32;

    f32x4 acc[2][2];
    for (int i = 0; i < 2; ++i)
        for (int j = 0; j < 2; ++j)
            acc[i][j] = (f32x4){0.f, 0.f, 0.f, 0.f};

    for (int kk = 0; kk < HID_F; kk += 32) {
        bf16x8 a[2], b[2];
        for (int i = 0; i < 2; ++i) {
            int m = m0 + i * 16 + lm;
            if (m > N_NODES - 1) m = N_NODES - 1;
            a[i] = *(const bf16x8*)(h1 + (size_t)m * HID_F + kk + quad * 8);
        }
        for (int j = 0; j < 2; ++j) {
            int n = n0 + j * 16 + lm;
            b[j] = *(const bf16x8*)(w2t + (size_t)n * HID_F + kk + quad * 8);
        }
        for (int i = 0; i < 2; ++i)
            for (int j = 0; j < 2; ++j)
                acc[i][j] = __builtin_amdgcn_mfma_f32_16x16x32_bf16(a[i], b[j], acc[i][j], 0, 0, 0);
    }

    for (int i = 0; i < 2; ++i)
        for (int j = 0; j < 2; ++j) {
            int n = n0 + j * 16 + lm;
            float bias = b2[n];
            for (int r = 0; r < 4; ++r) {
                int m = m0 + i * 16 + quad * 4 + r;
                if (m < N_NODES) {
                    float v = acc[i][j][r] + bias;
                    h0[(size_t)m * OUT_F + n] = f2bf(v);
                }
            }
        }
}

// ---------------- CSR build ----------------
__global__ void count_edges(const int* __restrict__ row, int* __restrict__ cnt) {
    int e = blockIdx.x * blockDim.x + threadIdx.x;
    if (e < N_EDGES) atomicAdd(&cnt[row[e]], 1);
}

// single-block scan: rowptr[0]=0, rowptr[i+1] = prefix-inclusive(cnt[0..i])
__global__ __launch_bounds__(1024) void scan_kernel(const int* __restrict__ cnt,
                                                    int* __restrict__ rowptr, int n) {
    __shared__ int warpsum[16];
    __shared__ int sbase;
    int tid = threadIdx.x;
    if (tid == 0) { sbase = 0; rowptr[0] = 0; }
    __syncthreads();
    for (int i0 = 0; i0 < n; i0 += 1024) {
        int i = i0 + tid;
        int v = (i < n) ? cnt[i] : 0;
        int incl = v;
        for (int d = 1; d < 64; d <<= 1) {
            int t = __shfl_up(incl, d);
            if ((tid & 63) >= d) incl += t;
        }
        int wid = tid >> 6;
        if ((tid & 63) == 63) warpsum[wid] = incl;
        __syncthreads();
        if (wid == 0) {
            int wv = (tid < 16) ? warpsum[tid] : 0;
            for (int d = 1; d < 16; d <<= 1) {
                int t = __shfl_up(wv, d);
                if ((tid & 63) >= d) wv += t;
            }
            if (tid < 16) warpsum[tid] = wv;
        }
        __syncthreads();
        int waveoff = (wid > 0) ? warpsum[wid - 1] : 0;
        int total   = warpsum[15];
        int base    = sbase;
        if (i < n) rowptr[i + 1] = base + waveoff + incl;
        __syncthreads();
        if (tid == 0) sbase = base + total;
        __syncthreads();
    }
}

__global__ void cursor_init(const int* __restrict__ rowptr, int* __restrict__ cur) {
    int i = blockIdx.x * blockDim.x + threadIdx.x;
    if (i < N_NODES) cur[i] = rowptr[i];
}

__global__ void scatter_edges(const int* __restrict__ row, const int* __restrict__ col,
                              const float* __restrict__ ew, int* __restrict__ cur,
                              int2* __restrict__ colw) {
    int e = blockIdx.x * blockDim.x + threadIdx.x;
    if (e < N_EDGES) {
        int p = atomicAdd(&cur[row[e]], 1);
        colw[p] = make_int2(col[e], __float_as_int(ew[e]));
    }
}

// ---------------- propagation ----------------
// One wave per row. 64 lanes = 4 edge-slots x 16 feature-quads.
// Lane handles features [4*hf, 4*hf+3] of edge slot (lane>>4).
// Main loop processes 4 edges/iteration guard-free; tail guarded.
// Partial sums combined with shfl_xor(16) + shfl_xor(32).
__global__ __launch_bounds__(256) void prop(const unsigned short* __restrict__ hin,
                                            const int* __restrict__ rowptr,
                                            const int2* __restrict__ colw,
                                            unsigned short* __restrict__ hout,
                                            float* __restrict__ fout, int is_final) {
    int lane = threadIdx.x & 63;
    int r = blockIdx.x * 4 + (threadIdx.x >> 6);
    int hf   = lane & 15;    // feature quad index
    int slot = lane >> 4;    // 0..3

    int s = rowptr[r];
    int e = rowptr[r + 1];

    float ax = 0.f, ay = 0.f, az = 0.f, aw = 0.f;
    int nfull = (e - s) & ~3;
    int i = s;
    #pragma unroll 2
    for (; i < s + nfull; i += 4) {
        int2 cw = colw[i + slot];
        float w = __int_as_float(cw.y);
        ushort4 p = *(const ushort4*)(hin + (size_t)cw.x * OUT_F + 4 * hf);
        ax += w * bf2f(p.x); ay += w * bf2f(p.y);
        az += w * bf2f(p.z); aw += w * bf2f(p.w);
    }
    {   // tail (0..3 edges)
        int ei = i + slot;
        if (ei < e) {
            int2 cw = colw[ei];
            float w = __int_as_float(cw.y);
            ushort4 p = *(const ushort4*)(hin + (size_t)cw.x * OUT_F + 4 * hf);
            ax += w * bf2f(p.x); ay += w * bf2f(p.y);
            az += w * bf2f(p.z); aw += w * bf2f(p.w);
        }
    }
    // combine the 4 edge-slots
    ax += __shfl_xor(ax, 16); ay += __shfl_xor(ay, 16);
    az += __shfl_xor(az, 16); aw += __shfl_xor(aw, 16);
    ax += __shfl_xor(ax, 32); ay += __shfl_xor(ay, 32);
    az += __shfl_xor(az, 32); aw += __shfl_xor(aw, 32);

    // residual term
    ushort4 ps = *(const ushort4*)(hin + (size_t)r * OUT_F + 4 * hf);
    float rx = 0.99f * ax + 0.01f * bf2f(ps.x);
    float ry = 0.99f * ay + 0.01f * bf2f(ps.y);
    float rz = 0.99f * az + 0.01f * bf2f(ps.z);
    float rw = 0.99f * aw + 0.01f * bf2f(ps.w);

    if (slot == 0) {
        size_t o = (size_t)r * OUT_F + 4 * hf;
        if (is_final) {
            *(float4*)(fout + o) = make_float4(rx, ry, rz, rw);
        } else {
            ushort4 pk;
            pk.x = f2bf(rx); pk.y = f2bf(ry); pk.z = f2bf(rz); pk.w = f2bf(rw);
            *(ushort4*)(hout + o) = pk;
        }
    }
}

extern "C" void kernel_launch(void* const* d_in, const int* in_sizes, int n_in,
                              void* d_out, int out_size, void* d_ws, size_t ws_size,
                              hipStream_t stream) {
    (void)in_sizes; (void)n_in; (void)out_size; (void)ws_size;
    const float* x  = (const float*)d_in[0];
    const float* W1 = (const float*)d_in[1];
    const float* b1 = (const float*)d_in[2];
    const float* W2 = (const float*)d_in[3];
    const float* b2 = (const float*)d_in[4];
    const float* ew = (const float*)d_in[5];
    const int*  row = (const int*)d_in[6];
    const int*  col = (const int*)d_in[7];
    float* out = (float*)d_out;

    char* ws = (char*)d_ws;
    size_t off = 0;
    auto alloc = [&](size_t b) { char* p = ws + off; off += (b + 255) & ~(size_t)255; return p; };
    unsigned short* w1t = (unsigned short*)alloc((size_t)IN_F * HID_F * 2);
    unsigned short* w2t = (unsigned short*)alloc((size_t)HID_F * OUT_F * 2);
    unsigned short* h1  = (unsigned short*)alloc((size_t)N_NODES * HID_F * 2);
    unsigned short* hb0 = (unsigned short*)alloc((size_t)N_NODES * OUT_F * 2);
    unsigned short* hb1 = (unsigned short*)alloc((size_t)N_NODES * OUT_F * 2);
    int*  rowptr = (int*)alloc((size_t)(N_NODES + 1) * 4);
    int*  cnt    = (int*)alloc((size_t)N_NODES * 4);
    int2* colw   = (int2*)alloc((size_t)N_EDGES * 8);

    cast_transpose_w1<<<(IN_F * HID_F + 255) / 256, 256, 0, stream>>>(W1, w1t);
    cast_transpose_w2<<<(HID_F * OUT_F + 255) / 256, 256, 0, stream>>>(W2, w2t);
    gemm1<<<(N_NODES + 63) / 64, 512, 0, stream>>>(x, w1t, b1, h1);
    gemm2<<<(N_NODES + 63) / 64, 256, 0, stream>>>(h1, w2t, b2, hb0);

    hipMemsetAsync(cnt, 0, (size_t)N_NODES * 4, stream);
    count_edges<<<(N_EDGES + 255) / 256, 256, 0, stream>>>(row, cnt);
    scan_kernel<<<1, 1024, 0, stream>>>(cnt, rowptr, N_NODES);
    cursor_init<<<(N_NODES + 255) / 256, 256, 0, stream>>>(rowptr, cnt);
    scatter_edges<<<(N_EDGES + 255) / 256, 256, 0, stream>>>(row, col, ew, cnt, colw);

    const unsigned short* pin = hb0;
    for (int s = 0; s < 10; ++s) {
        int last = (s == 9);
        unsigned short* pout = (s & 1) ? hb0 : hb1;
        prop<<<N_NODES / 4, 256, 0, stream>>>(pin, rowptr, colw, pout, out, last);
        pin = pout;
    }
}

// Round 3
// 1467.140 us; speedup vs baseline: 1.8236x; 1.1454x over previous
//
#include <hip/hip_runtime.h>

// APPNP: h0 = relu(x@W1+b1)@W2+b2 ; 10x h = 0.99*SpMM(h) + 0.01*h
// bf16 MFMA GEMMs, on-device CSR build, gather SpMM with bf16 h storage.
// R3: prop = 8 edges/wave-iter (8 slots x 8 feature-octets, 16B gather/lane);
//     hierarchical 3-kernel prefix scan replaces single-block scan.

#define N_NODES 100000
#define N_EDGES 3200000
#define IN_F    512
#define HID_F   256
#define OUT_F   64

typedef short bf16x8 __attribute__((ext_vector_type(8)));
typedef float f32x4  __attribute__((ext_vector_type(4)));

__device__ __forceinline__ unsigned short f2bf(float f) {
    unsigned int u = __float_as_uint(f);
    unsigned int r = (u + 0x7FFFu + ((u >> 16) & 1u)) >> 16;  // RNE
    return (unsigned short)r;
}
__device__ __forceinline__ float bf2f(unsigned short h) {
    return __uint_as_float(((unsigned int)h) << 16);
}

// ---------------- weight cast+transpose ----------------
__global__ void cast_transpose_w1(const float* __restrict__ w, unsigned short* __restrict__ wt) {
    int idx = blockIdx.x * blockDim.x + threadIdx.x;   // over 512*256
    if (idx >= IN_F * HID_F) return;
    int k = idx / HID_F, n = idx % HID_F;
    wt[(size_t)n * IN_F + k] = f2bf(w[idx]);           // W1T [HID_F][IN_F]
}
__global__ void cast_transpose_w2(const float* __restrict__ w, unsigned short* __restrict__ wt) {
    int idx = blockIdx.x * blockDim.x + threadIdx.x;   // over 256*64
    if (idx >= HID_F * OUT_F) return;
    int k = idx / OUT_F, n = idx % OUT_F;
    wt[(size_t)n * HID_F + k] = f2bf(w[idx]);          // W2T [OUT_F][HID_F]
}

// ---------------- GEMM1: h1 = relu(x @ W1 + b1), bf16 out ----------------
__global__ __launch_bounds__(512) void gemm1(const float* __restrict__ x,
                                             const unsigned short* __restrict__ w1t,
                                             const float* __restrict__ b1,
                                             unsigned short* __restrict__ h1) {
    int tid  = threadIdx.x;
    int lane = tid & 63;
    int w    = tid >> 6;     // 0..7
    int wm   = w >> 2;       // 0..1
    int wn   = w & 3;        // 0..3
    int quad = lane >> 4;    // 0..3
    int lm   = lane & 15;
    int m0 = blockIdx.x * 64 + wm * 32;
    int n0 = wn * 64;

    f32x4 acc[2][4];
    for (int i = 0; i < 2; ++i)
        for (int j = 0; j < 4; ++j)
            acc[i][j] = (f32x4){0.f, 0.f, 0.f, 0.f};

    for (int kk = 0; kk < IN_F; kk += 32) {
        bf16x8 a[2], b[4];
        for (int i = 0; i < 2; ++i) {
            int m = m0 + i * 16 + lm;
            if (m > N_NODES - 1) m = N_NODES - 1;            // clamp loads, mask stores
            const float* ap = x + (size_t)m * IN_F + kk + quad * 8;
            float4 f0 = *(const float4*)ap;
            float4 f1 = *(const float4*)(ap + 4);
            union { bf16x8 v; unsigned short u[8]; } t;
            t.u[0] = f2bf(f0.x); t.u[1] = f2bf(f0.y); t.u[2] = f2bf(f0.z); t.u[3] = f2bf(f0.w);
            t.u[4] = f2bf(f1.x); t.u[5] = f2bf(f1.y); t.u[6] = f2bf(f1.z); t.u[7] = f2bf(f1.w);
            a[i] = t.v;
        }
        for (int j = 0; j < 4; ++j) {
            int n = n0 + j * 16 + lm;
            b[j] = *(const bf16x8*)(w1t + (size_t)n * IN_F + kk + quad * 8);
        }
        for (int i = 0; i < 2; ++i)
            for (int j = 0; j < 4; ++j)
                acc[i][j] = __builtin_amdgcn_mfma_f32_16x16x32_bf16(a[i], b[j], acc[i][j], 0, 0, 0);
    }

    for (int i = 0; i < 2; ++i)
        for (int j = 0; j < 4; ++j) {
            int n = n0 + j * 16 + lm;
            float bias = b1[n];
            for (int r = 0; r < 4; ++r) {
                int m = m0 + i * 16 + quad * 4 + r;   // C/D: row=(lane>>4)*4+reg, col=lane&15
                if (m < N_NODES) {
                    float v = acc[i][j][r] + bias;
                    v = v > 0.f ? v : 0.f;
                    h1[(size_t)m * HID_F + n] = f2bf(v);
                }
            }
        }
}

// ---------------- GEMM2: h0 = h1 @ W2 + b2, bf16 out ----------------
__global__ __launch_bounds__(256) void gemm2(const unsigned short* __restrict__ h1,
                                             const unsigned short* __restrict__ w2t,
                                             const float* __restrict__ b2,
                                             unsigned short* __restrict__ h0) {
    int tid  = threadIdx.x;
    int lane = tid & 63;
    int w    = tid >> 6;     // 0..3
    int wm   = w >> 1;       // 0..1
    int wn   = w & 1;        // 0..1
    int quad = lane >> 4;
    int lm   = lane & 15;
    int m0 = blockIdx.x * 64 + wm * 32;
    int n0 = wn * 32;

    f32x4 acc[2][2];
    for (int i = 0; i < 2; ++i)
        for (int j = 0; j < 2; ++j)
            acc[i][j] = (f32x4){0.f, 0.f, 0.f, 0.f};

    for (int kk = 0; kk < HID_F; kk += 32) {
        bf16x8 a[2], b[2];
        for (int i = 0; i < 2; ++i) {
            int m = m0 + i * 16 + lm;
            if (m > N_NODES - 1) m = N_NODES - 1;
            a[i] = *(const bf16x8*)(h1 + (size_t)m * HID_F + kk + quad * 8);
        }
        for (int j = 0; j < 2; ++j) {
            int n = n0 + j * 16 + lm;
            b[j] = *(const bf16x8*)(w2t + (size_t)n * HID_F + kk + quad * 8);
        }
        for (int i = 0; i < 2; ++i)
            for (int j = 0; j < 2; ++j)
                acc[i][j] = __builtin_amdgcn_mfma_f32_16x16x32_bf16(a[i], b[j], acc[i][j], 0, 0, 0);
    }

    for (int i = 0; i < 2; ++i)
        for (int j = 0; j < 2; ++j) {
            int n = n0 + j * 16 + lm;
            float bias = b2[n];
            for (int r = 0; r < 4; ++r) {
                int m = m0 + i * 16 + quad * 4 + r;
                if (m < N_NODES) {
                    float v = acc[i][j][r] + bias;
                    h0[(size_t)m * OUT_F + n] = f2bf(v);
                }
            }
        }
}

// ---------------- CSR build ----------------
__global__ void count_edges(const int* __restrict__ row, int* __restrict__ cnt) {
    int e = blockIdx.x * blockDim.x + threadIdx.x;
    if (e < N_EDGES) atomicAdd(&cnt[row[e]], 1);
}

// hierarchical scan: rowptr[i+1] = inclusive-prefix(cnt[0..i]), rowptr[0]=0
__global__ __launch_bounds__(256) void scan_local(const int* __restrict__ cnt,
                                                  int* __restrict__ rowptr,
                                                  int* __restrict__ bsum, int n) {
    __shared__ int wsum[4];
    int tid = threadIdx.x;
    int i = blockIdx.x * 256 + tid;
    int v = (i < n) ? cnt[i] : 0;
    int incl = v;
    for (int d = 1; d < 64; d <<= 1) {
        int t = __shfl_up(incl, d);
        if ((tid & 63) >= d) incl += t;
    }
    int wid = tid >> 6;
    if ((tid & 63) == 63) wsum[wid] = incl;
    __syncthreads();
    if (tid == 0) {
        int a = 0;
        for (int k = 0; k < 4; ++k) { int t = wsum[k]; wsum[k] = a; a += t; }
        bsum[blockIdx.x] = a;
    }
    __syncthreads();
    if (i < n) rowptr[i + 1] = incl + wsum[wid];   // block offset added later
}

__global__ __launch_bounds__(512) void scan_bsum(const int* __restrict__ bsum,
                                                 int* __restrict__ boff, int nb) {
    __shared__ int wsum[8];
    int tid = threadIdx.x;
    int v = (tid < nb) ? bsum[tid] : 0;
    int incl = v;
    for (int d = 1; d < 64; d <<= 1) {
        int t = __shfl_up(incl, d);
        if ((tid & 63) >= d) incl += t;
    }
    int wid = tid >> 6;
    if ((tid & 63) == 63) wsum[wid] = incl;
    __syncthreads();
    if (tid == 0) {
        int a = 0;
        for (int k = 0; k < 8; ++k) { int t = wsum[k]; wsum[k] = a; a += t; }
    }
    __syncthreads();
    if (tid < nb) boff[tid] = incl - v + wsum[wid];   // exclusive
}

__global__ __launch_bounds__(256) void scan_add(int* __restrict__ rowptr,
                                                const int* __restrict__ boff, int n) {
    int i = blockIdx.x * 256 + threadIdx.x;
    if (i == 0) rowptr[0] = 0;
    if (i < n) rowptr[i + 1] += boff[blockIdx.x];
}

__global__ void cursor_init(const int* __restrict__ rowptr, int* __restrict__ cur) {
    int i = blockIdx.x * blockDim.x + threadIdx.x;
    if (i < N_NODES) cur[i] = rowptr[i];
}

__global__ void scatter_edges(const int* __restrict__ row, const int* __restrict__ col,
                              const float* __restrict__ ew, int* __restrict__ cur,
                              int2* __restrict__ colw) {
    int e = blockIdx.x * blockDim.x + threadIdx.x;
    if (e < N_EDGES) {
        int p = atomicAdd(&cur[row[e]], 1);
        colw[p] = make_int2(col[e], __float_as_int(ew[e]));
    }
}

// ---------------- propagation ----------------
// One wave per row. 64 lanes = 8 edge-slots x 8 feature-octets.
// Lane (slot=lane>>3, fe=lane&7) handles features [8*fe, 8*fe+7] of edge
// slot: 16B bf16x8 gather per lane, 8 lanes cover a full 128B h-row.
// colw[i+slot]: 8 distinct addrs/wave (contiguous 64B), broadcast to 8 lanes.
// Main loop 8 edges/iter guard-free; tail guarded; shfl_xor(8,16,32) combine.
__global__ __launch_bounds__(256) void prop(const unsigned short* __restrict__ hin,
                                            const int* __restrict__ rowptr,
                                            const int2* __restrict__ colw,
                                            unsigned short* __restrict__ hout,
                                            float* __restrict__ fout, int is_final) {
    int lane = threadIdx.x & 63;
    int r = blockIdx.x * 4 + (threadIdx.x >> 6);
    int fe   = lane & 7;     // feature octet index
    int slot = lane >> 3;    // 0..7

    int s = rowptr[r];
    int e = rowptr[r + 1];
    const unsigned short* hfe = hin + 8 * fe;

    float af[8];
    #pragma unroll
    for (int k = 0; k < 8; ++k) af[k] = 0.f;

    int n8 = (e - s) & ~7;
    int i = s;
    #pragma unroll 2
    for (; i < s + n8; i += 8) {
        int2 cw = colw[i + slot];
        float w = __int_as_float(cw.y);
        bf16x8 p = *(const bf16x8*)(hfe + (size_t)cw.x * OUT_F);
        #pragma unroll
        for (int k = 0; k < 8; ++k)
            af[k] += w * bf2f((unsigned short)p[k]);
    }
    {   // tail (0..7 edges)
        int ei = i + slot;
        if (ei < e) {
            int2 cw = colw[ei];
            float w = __int_as_float(cw.y);
            bf16x8 p = *(const bf16x8*)(hfe + (size_t)cw.x * OUT_F);
            #pragma unroll
            for (int k = 0; k < 8; ++k)
                af[k] += w * bf2f((unsigned short)p[k]);
        }
    }
    // combine the 8 edge-slots
    #pragma unroll
    for (int k = 0; k < 8; ++k) {
        af[k] += __shfl_xor(af[k], 8);
        af[k] += __shfl_xor(af[k], 16);
        af[k] += __shfl_xor(af[k], 32);
    }

    if (slot == 0) {
        bf16x8 ps = *(const bf16x8*)(hin + (size_t)r * OUT_F + 8 * fe);
        float rr[8];
        #pragma unroll
        for (int k = 0; k < 8; ++k)
            rr[k] = 0.99f * af[k] + 0.01f * bf2f((unsigned short)ps[k]);
        size_t o = (size_t)r * OUT_F + 8 * fe;
        if (is_final) {
            *(float4*)(fout + o)     = make_float4(rr[0], rr[1], rr[2], rr[3]);
            *(float4*)(fout + o + 4) = make_float4(rr[4], rr[5], rr[6], rr[7]);
        } else {
            union { bf16x8 v; unsigned short u[8]; } pk;
            #pragma unroll
            for (int k = 0; k < 8; ++k) pk.u[k] = f2bf(rr[k]);
            *(bf16x8*)(hout + o) = pk.v;
        }
    }
}

extern "C" void kernel_launch(void* const* d_in, const int* in_sizes, int n_in,
                              void* d_out, int out_size, void* d_ws, size_t ws_size,
                              hipStream_t stream) {
    (void)in_sizes; (void)n_in; (void)out_size; (void)ws_size;
    const float* x  = (const float*)d_in[0];
    const float* W1 = (const float*)d_in[1];
    const float* b1 = (const float*)d_in[2];
    const float* W2 = (const float*)d_in[3];
    const float* b2 = (const float*)d_in[4];
    const float* ew = (const float*)d_in[5];
    const int*  row = (const int*)d_in[6];
    const int*  col = (const int*)d_in[7];
    float* out = (float*)d_out;

    char* ws = (char*)d_ws;
    size_t off = 0;
    auto alloc = [&](size_t b) { char* p = ws + off; off += (b + 255) & ~(size_t)255; return p; };
    unsigned short* w1t = (unsigned short*)alloc((size_t)IN_F * HID_F * 2);
    unsigned short* w2t = (unsigned short*)alloc((size_t)HID_F * OUT_F * 2);
    unsigned short* h1  = (unsigned short*)alloc((size_t)N_NODES * HID_F * 2);
    unsigned short* hb0 = (unsigned short*)alloc((size_t)N_NODES * OUT_F * 2);
    unsigned short* hb1 = (unsigned short*)alloc((size_t)N_NODES * OUT_F * 2);
    int*  rowptr = (int*)alloc((size_t)(N_NODES + 1) * 4);
    int*  cnt    = (int*)alloc((size_t)N_NODES * 4);
    int*  bsum   = (int*)alloc(512 * 4);
    int*  boff   = (int*)alloc(512 * 4);
    int2* colw   = (int2*)alloc((size_t)N_EDGES * 8);

    const int NB = (N_NODES + 255) / 256;   // 391

    cast_transpose_w1<<<(IN_F * HID_F + 255) / 256, 256, 0, stream>>>(W1, w1t);
    cast_transpose_w2<<<(HID_F * OUT_F + 255) / 256, 256, 0, stream>>>(W2, w2t);
    gemm1<<<(N_NODES + 63) / 64, 512, 0, stream>>>(x, w1t, b1, h1);
    gemm2<<<(N_NODES + 63) / 64, 256, 0, stream>>>(h1, w2t, b2, hb0);

    hipMemsetAsync(cnt, 0, (size_t)N_NODES * 4, stream);
    count_edges<<<(N_EDGES + 255) / 256, 256, 0, stream>>>(row, cnt);
    scan_local<<<NB, 256, 0, stream>>>(cnt, rowptr, bsum, N_NODES);
    scan_bsum<<<1, 512, 0, stream>>>(bsum, boff, NB);
    scan_add<<<NB, 256, 0, stream>>>(rowptr, boff, N_NODES);
    cursor_init<<<(N_NODES + 255) / 256, 256, 0, stream>>>(rowptr, cnt);
    scatter_edges<<<(N_EDGES + 255) / 256, 256, 0, stream>>>(row, col, ew, cnt, colw);

    const unsigned short* pin = hb0;
    for (int s = 0; s < 10; ++s) {
        int last = (s == 9);
        unsigned short* pout = (s & 1) ? hb0 : hb1;
        prop<<<N_NODES / 4, 256, 0, stream>>>(pin, rowptr, colw, pout, out, last);
        pin = pout;
    }
}

// Round 4
// 1440.147 us; speedup vs baseline: 1.8577x; 1.0187x over previous
//
#include <hip/hip_runtime.h>

// APPNP: h0 = relu(x@W1+b1)@W2+b2 ; 10x h = 0.99*SpMM(h) + 0.01*h
// bf16 MFMA GEMMs, on-device CSR build, gather SpMM with bf16 h storage.
// R4: two-phase bucket sort replaces random scatter_edges (8x write amp);
//     LDS cursors in pass B; 32-bit gather index in prop.

#define N_NODES 100000
#define N_EDGES 3200000
#define IN_F    512
#define HID_F   256
#define OUT_F   64
#define NBKT    ((N_NODES + 63) / 64)   // 1563 coarse buckets (row>>6)

typedef short bf16x8 __attribute__((ext_vector_type(8)));
typedef float f32x4  __attribute__((ext_vector_type(4)));

__device__ __forceinline__ unsigned short f2bf(float f) {
    unsigned int u = __float_as_uint(f);
    unsigned int r = (u + 0x7FFFu + ((u >> 16) & 1u)) >> 16;  // RNE
    return (unsigned short)r;
}
__device__ __forceinline__ float bf2f(unsigned short h) {
    return __uint_as_float(((unsigned int)h) << 16);
}

// ---------------- weight cast+transpose ----------------
__global__ void cast_transpose_w1(const float* __restrict__ w, unsigned short* __restrict__ wt) {
    int idx = blockIdx.x * blockDim.x + threadIdx.x;   // over 512*256
    if (idx >= IN_F * HID_F) return;
    int k = idx / HID_F, n = idx % HID_F;
    wt[(size_t)n * IN_F + k] = f2bf(w[idx]);           // W1T [HID_F][IN_F]
}
__global__ void cast_transpose_w2(const float* __restrict__ w, unsigned short* __restrict__ wt) {
    int idx = blockIdx.x * blockDim.x + threadIdx.x;   // over 256*64
    if (idx >= HID_F * OUT_F) return;
    int k = idx / OUT_F, n = idx % OUT_F;
    wt[(size_t)n * HID_F + k] = f2bf(w[idx]);          // W2T [OUT_F][HID_F]
}

// ---------------- GEMM1: h1 = relu(x @ W1 + b1), bf16 out ----------------
__global__ __launch_bounds__(512) void gemm1(const float* __restrict__ x,
                                             const unsigned short* __restrict__ w1t,
                                             const float* __restrict__ b1,
                                             unsigned short* __restrict__ h1) {
    int tid  = threadIdx.x;
    int lane = tid & 63;
    int w    = tid >> 6;     // 0..7
    int wm   = w >> 2;       // 0..1
    int wn   = w & 3;        // 0..3
    int quad = lane >> 4;    // 0..3
    int lm   = lane & 15;
    int m0 = blockIdx.x * 64 + wm * 32;
    int n0 = wn * 64;

    f32x4 acc[2][4];
    for (int i = 0; i < 2; ++i)
        for (int j = 0; j < 4; ++j)
            acc[i][j] = (f32x4){0.f, 0.f, 0.f, 0.f};

    for (int kk = 0; kk < IN_F; kk += 32) {
        bf16x8 a[2], b[4];
        for (int i = 0; i < 2; ++i) {
            int m = m0 + i * 16 + lm;
            if (m > N_NODES - 1) m = N_NODES - 1;            // clamp loads, mask stores
            const float* ap = x + (size_t)m * IN_F + kk + quad * 8;
            float4 f0 = *(const float4*)ap;
            float4 f1 = *(const float4*)(ap + 4);
            union { bf16x8 v; unsigned short u[8]; } t;
            t.u[0] = f2bf(f0.x); t.u[1] = f2bf(f0.y); t.u[2] = f2bf(f0.z); t.u[3] = f2bf(f0.w);
            t.u[4] = f2bf(f1.x); t.u[5] = f2bf(f1.y); t.u[6] = f2bf(f1.z); t.u[7] = f2bf(f1.w);
            a[i] = t.v;
        }
        for (int j = 0; j < 4; ++j) {
            int n = n0 + j * 16 + lm;
            b[j] = *(const bf16x8*)(w1t + (size_t)n * IN_F + kk + quad * 8);
        }
        for (int i = 0; i < 2; ++i)
            for (int j = 0; j < 4; ++j)
                acc[i][j] = __builtin_amdgcn_mfma_f32_16x16x32_bf16(a[i], b[j], acc[i][j], 0, 0, 0);
    }

    for (int i = 0; i < 2; ++i)
        for (int j = 0; j < 4; ++j) {
            int n = n0 + j * 16 + lm;
            float bias = b1[n];
            for (int r = 0; r < 4; ++r) {
                int m = m0 + i * 16 + quad * 4 + r;   // C/D: row=(lane>>4)*4+reg, col=lane&15
                if (m < N_NODES) {
                    float v = acc[i][j][r] + bias;
                    v = v > 0.f ? v : 0.f;
                    h1[(size_t)m * HID_F + n] = f2bf(v);
                }
            }
        }
}

// ---------------- GEMM2: h0 = h1 @ W2 + b2, bf16 out ----------------
__global__ __launch_bounds__(256) void gemm2(const unsigned short* __restrict__ h1,
                                             const unsigned short* __restrict__ w2t,
                                             const float* __restrict__ b2,
                                             unsigned short* __restrict__ h0) {
    int tid  = threadIdx.x;
    int lane = tid & 63;
    int w    = tid >> 6;     // 0..3
    int wm   = w >> 1;       // 0..1
    int wn   = w & 1;        // 0..1
    int quad = lane >> 4;
    int lm   = lane & 15;
    int m0 = blockIdx.x * 64 + wm * 32;
    int n0 = wn * 32;

    f32x4 acc[2][2];
    for (int i = 0; i < 2; ++i)
        for (int j = 0; j < 2; ++j)
            acc[i][j] = (f32x4){0.f, 0.f, 0.f, 0.f};

    for (int kk = 0; kk < HID_F; kk += 32) {
        bf16x8 a[2], b[2];
        for (int i = 0; i < 2; ++i) {
            int m = m0 + i * 16 + lm;
            if (m > N_NODES - 1) m = N_NODES - 1;
            a[i] = *(const bf16x8*)(h1 + (size_t)m * HID_F + kk + quad * 8);
        }
        for (int j = 0; j < 2; ++j) {
            int n = n0 + j * 16 + lm;
            b[j] = *(const bf16x8*)(w2t + (size_t)n * HID_F + kk + quad * 8);
        }
        for (int i = 0; i < 2; ++i)
            for (int j = 0; j < 2; ++j)
                acc[i][j] = __builtin_amdgcn_mfma_f32_16x16x32_bf16(a[i], b[j], acc[i][j], 0, 0, 0);
    }

    for (int i = 0; i < 2; ++i)
        for (int j = 0; j < 2; ++j) {
            int n = n0 + j * 16 + lm;
            float bias = b2[n];
            for (int r = 0; r < 4; ++r) {
                int m = m0 + i * 16 + quad * 4 + r;
                if (m < N_NODES) {
                    float v = acc[i][j][r] + bias;
                    h0[(size_t)m * OUT_F + n] = f2bf(v);
                }
            }
        }
}

// ---------------- CSR build ----------------
__global__ void count_edges(const int* __restrict__ row, int* __restrict__ cnt) {
    int e = blockIdx.x * blockDim.x + threadIdx.x;
    if (e < N_EDGES) atomicAdd(&cnt[row[e]], 1);
}

// hierarchical scan: rowptr[i+1] = inclusive-prefix(cnt[0..i]), rowptr[0]=0
__global__ __launch_bounds__(256) void scan_local(const int* __restrict__ cnt,
                                                  int* __restrict__ rowptr,
                                                  int* __restrict__ bsum, int n) {
    __shared__ int wsum[4];
    int tid = threadIdx.x;
    int i = blockIdx.x * 256 + tid;
    int v = (i < n) ? cnt[i] : 0;
    int incl = v;
    for (int d = 1; d < 64; d <<= 1) {
        int t = __shfl_up(incl, d);
        if ((tid & 63) >= d) incl += t;
    }
    int wid = tid >> 6;
    if ((tid & 63) == 63) wsum[wid] = incl;
    __syncthreads();
    if (tid == 0) {
        int a = 0;
        for (int k = 0; k < 4; ++k) { int t = wsum[k]; wsum[k] = a; a += t; }
        bsum[blockIdx.x] = a;
    }
    __syncthreads();
    if (i < n) rowptr[i + 1] = incl + wsum[wid];   // block offset added later
}

__global__ __launch_bounds__(512) void scan_bsum(const int* __restrict__ bsum,
                                                 int* __restrict__ boff, int nb) {
    __shared__ int wsum[8];
    int tid = threadIdx.x;
    int v = (tid < nb) ? bsum[tid] : 0;
    int incl = v;
    for (int d = 1; d < 64; d <<= 1) {
        int t = __shfl_up(incl, d);
        if ((tid & 63) >= d) incl += t;
    }
    int wid = tid >> 6;
    if ((tid & 63) == 63) wsum[wid] = incl;
    __syncthreads();
    if (tid == 0) {
        int a = 0;
        for (int k = 0; k < 8; ++k) { int t = wsum[k]; wsum[k] = a; a += t; }
    }
    __syncthreads();
    if (tid < nb) boff[tid] = incl - v + wsum[wid];   // exclusive
}

__global__ __launch_bounds__(256) void scan_add(int* __restrict__ rowptr,
                                                const int* __restrict__ boff, int n) {
    int i = blockIdx.x * 256 + threadIdx.x;
    if (i == 0) rowptr[0] = 0;
    if (i < n) rowptr[i + 1] += boff[blockIdx.x];
}

// coarse-bucket cursor init: bucket c region starts at rowptr[64c].
// Counters padded to one per 64B line (stride 16 ints).
__global__ void ccur_init(const int* __restrict__ rowptr, int* __restrict__ ccur) {
    int c = blockIdx.x * blockDim.x + threadIdx.x;
    if (c < NBKT) ccur[c * 16] = rowptr[c * 64];
}

// Pass A: scatter edges to coarse buckets (row>>6). Payload packed 8B:
// x = col | (row&63)<<17, y = weight bits. Active write set = 1563 lines.
__global__ void bucket_scatter(const int* __restrict__ row, const int* __restrict__ col,
                               const float* __restrict__ ew, int* __restrict__ ccur,
                               uint2* __restrict__ tmp) {
    int e = blockIdx.x * blockDim.x + threadIdx.x;
    if (e < N_EDGES) {
        int r = row[e];
        int c = r >> 6;
        int p = atomicAdd(&ccur[c * 16], 1);
        tmp[p] = make_uint2((unsigned)col[e] | ((unsigned)(r & 63) << 17),
                            __float_as_uint(ew[e]));
    }
}

// Pass B: one block per bucket; LDS cursors for the 64 exclusively-owned
// rows; contiguous read of bucket region, write within 16KB span.
__global__ __launch_bounds__(256) void bucket_sort(const uint2* __restrict__ tmp,
                                                   const int* __restrict__ rowptr,
                                                   int2* __restrict__ colw) {
    __shared__ int lcur[64];
    int c = blockIdx.x;
    int r0 = c * 64;
    int tid = threadIdx.x;
    int rend = r0 + 64; if (rend > N_NODES) rend = N_NODES;
    if (tid < 64) {
        int rr = r0 + tid;
        lcur[tid] = (rr < N_NODES) ? rowptr[rr] : 0;
    }
    __syncthreads();
    int s = rowptr[r0];
    int e = rowptr[rend];
    for (int i = s + tid; i < e; i += 256) {
        uint2 t = tmp[i];
        int rl = (t.x >> 17) & 63;
        int cc = t.x & 0x1FFFF;
        int p = atomicAdd(&lcur[rl], 1);
        colw[p] = make_int2(cc, (int)t.y);
    }
}

// ---------------- propagation ----------------
// One wave per row. 64 lanes = 8 edge-slots x 8 feature-octets.
// Lane (slot=lane>>3, fe=lane&7) handles features [8*fe, 8*fe+7] of edge
// slot: 16B bf16x8 gather per lane, 8 lanes cover a full 128B h-row.
__global__ __launch_bounds__(256) void prop(const unsigned short* __restrict__ hin,
                                            const int* __restrict__ rowptr,
                                            const int2* __restrict__ colw,
                                            unsigned short* __restrict__ hout,
                                            float* __restrict__ fout, int is_final) {
    int lane = threadIdx.x & 63;
    int r = blockIdx.x * 4 + (threadIdx.x >> 6);
    int fe   = lane & 7;     // feature octet index
    int slot = lane >> 3;    // 0..7

    int s = rowptr[r];
    int e = rowptr[r + 1];
    const unsigned short* hfe = hin + 8 * fe;

    float af[8];
    #pragma unroll
    for (int k = 0; k < 8; ++k) af[k] = 0.f;

    int n8 = (e - s) & ~7;
    int i = s;
    #pragma unroll 2
    for (; i < s + n8; i += 8) {
        int2 cw = colw[i + slot];
        float w = __int_as_float(cw.y);
        bf16x8 p = *(const bf16x8*)(hfe + (unsigned)cw.x * (unsigned)OUT_F);
        #pragma unroll
        for (int k = 0; k < 8; ++k)
            af[k] += w * bf2f((unsigned short)p[k]);
    }
    {   // tail (0..7 edges)
        int ei = i + slot;
        if (ei < e) {
            int2 cw = colw[ei];
            float w = __int_as_float(cw.y);
            bf16x8 p = *(const bf16x8*)(hfe + (unsigned)cw.x * (unsigned)OUT_F);
            #pragma unroll
            for (int k = 0; k < 8; ++k)
                af[k] += w * bf2f((unsigned short)p[k]);
        }
    }
    // combine the 8 edge-slots
    #pragma unroll
    for (int k = 0; k < 8; ++k) {
        af[k] += __shfl_xor(af[k], 8);
        af[k] += __shfl_xor(af[k], 16);
        af[k] += __shfl_xor(af[k], 32);
    }

    if (slot == 0) {
        bf16x8 ps = *(const bf16x8*)(hin + (unsigned)r * (unsigned)OUT_F + 8 * fe);
        float rr[8];
        #pragma unroll
        for (int k = 0; k < 8; ++k)
            rr[k] = 0.99f * af[k] + 0.01f * bf2f((unsigned short)ps[k]);
        size_t o = (size_t)r * OUT_F + 8 * fe;
        if (is_final) {
            *(float4*)(fout + o)     = make_float4(rr[0], rr[1], rr[2], rr[3]);
            *(float4*)(fout + o + 4) = make_float4(rr[4], rr[5], rr[6], rr[7]);
        } else {
            union { bf16x8 v; unsigned short u[8]; } pk;
            #pragma unroll
            for (int k = 0; k < 8; ++k) pk.u[k] = f2bf(rr[k]);
            *(bf16x8*)(hout + o) = pk.v;
        }
    }
}

extern "C" void kernel_launch(void* const* d_in, const int* in_sizes, int n_in,
                              void* d_out, int out_size, void* d_ws, size_t ws_size,
                              hipStream_t stream) {
    (void)in_sizes; (void)n_in; (void)out_size; (void)ws_size;
    const float* x  = (const float*)d_in[0];
    const float* W1 = (const float*)d_in[1];
    const float* b1 = (const float*)d_in[2];
    const float* W2 = (const float*)d_in[3];
    const float* b2 = (const float*)d_in[4];
    const float* ew = (const float*)d_in[5];
    const int*  row = (const int*)d_in[6];
    const int*  col = (const int*)d_in[7];
    float* out = (float*)d_out;

    char* ws = (char*)d_ws;
    size_t off = 0;
    auto alloc = [&](size_t b) { char* p = ws + off; off += (b + 255) & ~(size_t)255; return p; };
    unsigned short* w1t = (unsigned short*)alloc((size_t)IN_F * HID_F * 2);
    unsigned short* w2t = (unsigned short*)alloc((size_t)HID_F * OUT_F * 2);
    unsigned short* h1  = (unsigned short*)alloc((size_t)N_NODES * HID_F * 2);
    unsigned short* hb0 = (unsigned short*)alloc((size_t)N_NODES * OUT_F * 2);
    unsigned short* hb1 = (unsigned short*)alloc((size_t)N_NODES * OUT_F * 2);
    int*  rowptr = (int*)alloc((size_t)(N_NODES + 1) * 4);
    int*  cnt    = (int*)alloc((size_t)N_NODES * 4);
    int*  bsum   = (int*)alloc(512 * 4);
    int*  boff   = (int*)alloc(512 * 4);
    int*  ccur   = (int*)alloc((size_t)NBKT * 16 * 4);
    uint2* tmp   = (uint2*)alloc((size_t)N_EDGES * 8);
    int2* colw   = (int2*)alloc((size_t)N_EDGES * 8);

    const int NB = (N_NODES + 255) / 256;   // 391

    cast_transpose_w1<<<(IN_F * HID_F + 255) / 256, 256, 0, stream>>>(W1, w1t);
    cast_transpose_w2<<<(HID_F * OUT_F + 255) / 256, 256, 0, stream>>>(W2, w2t);
    gemm1<<<(N_NODES + 63) / 64, 512, 0, stream>>>(x, w1t, b1, h1);
    gemm2<<<(N_NODES + 63) / 64, 256, 0, stream>>>(h1, w2t, b2, hb0);

    hipMemsetAsync(cnt, 0, (size_t)N_NODES * 4, stream);
    count_edges<<<(N_EDGES + 255) / 256, 256, 0, stream>>>(row, cnt);
    scan_local<<<NB, 256, 0, stream>>>(cnt, rowptr, bsum, N_NODES);
    scan_bsum<<<1, 512, 0, stream>>>(bsum, boff, NB);
    scan_add<<<NB, 256, 0, stream>>>(rowptr, boff, N_NODES);
    ccur_init<<<(NBKT + 255) / 256, 256, 0, stream>>>(rowptr, ccur);
    bucket_scatter<<<(N_EDGES + 255) / 256, 256, 0, stream>>>(row, col, ew, ccur, tmp);
    bucket_sort<<<NBKT, 256, 0, stream>>>(tmp, rowptr, colw);

    const unsigned short* pin = hb0;
    for (int s = 0; s < 10; ++s) {
        int last = (s == 9);
        unsigned short* pout = (s & 1) ? hb0 : hb1;
        prop<<<N_NODES / 4, 256, 0, stream>>>(pin, rowptr, colw, pout, out, last);
        pin = pout;
    }
}